// Round 15
// baseline (73.739 us; speedup 1.0000x reference)
//
#include <hip/hip_runtime.h>
#include <hip/hip_fp16.h>
#include <math.h>

#define EPS 1e-4f
#define N_   32
#define CIN  128
#define L_   512
#define CP   64
#define P_   2000
#define NCLS 200

typedef __attribute__((ext_vector_type(8))) _Float16 f16x8;
typedef __attribute__((ext_vector_type(4))) float f32x4;

__device__ inline void gl_lds16(const void* g, void* l) {
    __builtin_amdgcn_global_load_lds(
        (const __attribute__((address_space(1))) unsigned int*)g,
        (__attribute__((address_space(3))) unsigned int*)l, 16, 0, 0);
}

// ---------------- Kernel 0: proto f32 -> f16 + p2 ----------------
__global__ __launch_bounds__(256) void k0_proto(const float* __restrict__ proto,
    unsigned short* __restrict__ ph, float* __restrict__ p2)
{
    const int tid = threadIdx.x;
    const int p   = blockIdx.x*4 + (tid >> 6);
    const int k   = tid & 63;
    float v = proto[(size_t)p*64 + k];
    ph[(size_t)p*64 + k] = __half_as_ushort(__float2half(v));
    float s = v*v;
    #pragma unroll
    for (int off = 32; off > 0; off >>= 1) s += __shfl_xor(s, off);
    if (k == 0) p2[p] = s;
}

// ---------------- Kernel 1: conv1x1 -> relu -> conv1x1 -> sigmoid -> f16 ----------------
// (R13/R5 structure; launched 3x this round as a timing probe — idempotent.)
__global__ __launch_bounds__(256) void k1_conv(const float* __restrict__ x,
    const float* __restrict__ W1, const float* __restrict__ b1,
    const float* __restrict__ W2, const float* __restrict__ b2,
    unsigned short* __restrict__ fT, float* __restrict__ x2buf)
{
    __shared__ float  xS[128*32];              // 16KB [c][l]
    __shared__ float4 W1s[64][32];             // 32KB [o][c4]
    __shared__ float4 W2s[64][16];             // 16KB [o][c4]
    __shared__ __align__(16) char scratch[8448];  // hS [64][33] f32  OR  fP [32][8] uint4
    __shared__ float  x2p[8][32];
    __shared__ float  b1s[64], b2s[64];

    float (*hS)[33]    = (float (*)[33])scratch;
    uint4 (*fP)[8]     = (uint4 (*)[8])scratch;

    const int tid = threadIdx.x;
    const int wv  = tid >> 6;
    const int n   = blockIdx.y;
    const int lg  = blockIdx.x;

    {
        const float* xbase = x + (size_t)n*CIN*L_ + lg*32;
        const int lane = tid & 63;
        #pragma unroll
        for (int i = 0; i < 4; ++i) {
            int blk = wv*4 + i;
            const float* src = xbase + (size_t)(blk*8 + (lane >> 3))*L_ + (lane & 7)*4;
            gl_lds16(src, &xS[blk*256]);
        }
    }

    const float4* W1g = (const float4*)W1;
    #pragma unroll
    for (int i = 0; i < 8; ++i) {
        int idx = tid + i*256;
        W1s[idx >> 5][idx & 31] = W1g[idx];
    }
    const float4* W2g = (const float4*)W2;
    #pragma unroll
    for (int i = 0; i < 4; ++i) {
        int idx = tid + i*256;
        W2s[idx >> 4][idx & 15] = W2g[idx];
    }
    if (tid < 64) { b1s[tid] = b1[tid]; b2s[tid] = b2[tid]; }
    __syncthreads();

    const int l  = tid & 31;
    const int og = tid >> 5;

    float h[8];
    #pragma unroll
    for (int o = 0; o < 8; ++o) h[o] = b1s[og*8 + o];

    #pragma unroll 8
    for (int c4 = 0; c4 < 32; ++c4) {
        float xv0 = xS[(c4*4+0)*32 + l];
        float xv1 = xS[(c4*4+1)*32 + l];
        float xv2 = xS[(c4*4+2)*32 + l];
        float xv3 = xS[(c4*4+3)*32 + l];
        #pragma unroll
        for (int o = 0; o < 8; ++o) {
            float4 w = W1s[og*8+o][c4];
            h[o] = fmaf(w.x, xv0, fmaf(w.y, xv1, fmaf(w.z, xv2, fmaf(w.w, xv3, h[o]))));
        }
    }
    __syncthreads();
    #pragma unroll
    for (int o = 0; o < 8; ++o)
        hS[og*8+o][l] = fmaxf(h[o], 0.0f);
    __syncthreads();

    float f[8];
    #pragma unroll
    for (int o = 0; o < 8; ++o) f[o] = b2s[og*8 + o];
    #pragma unroll 4
    for (int c4 = 0; c4 < 16; ++c4) {
        float h0 = hS[c4*4+0][l];
        float h1 = hS[c4*4+1][l];
        float h2 = hS[c4*4+2][l];
        float h3 = hS[c4*4+3][l];
        #pragma unroll
        for (int o = 0; o < 8; ++o) {
            float4 w = W2s[og*8+o][c4];
            f[o] = fmaf(w.x, h0, fmaf(w.y, h1, fmaf(w.z, h2, fmaf(w.w, h3, f[o]))));
        }
    }

    unsigned int pack[4];
    float s = 0.0f;
    #pragma unroll
    for (int o = 0; o < 8; ++o) {
        float v = 1.0f / (1.0f + expf(-f[o]));
        unsigned short hb = __half_as_ushort(__float2half(v));
        if (o & 1) pack[o>>1] |= ((unsigned)hb) << 16;
        else       pack[o>>1]  = hb;
        s = fmaf(v, v, s);
    }
    x2p[og][l] = s;
    __syncthreads();

    fP[l][og ^ (l & 7)] = make_uint4(pack[0],pack[1],pack[2],pack[3]);
    __syncthreads();

    uint4* g4 = (uint4*)fT + ((size_t)(n*L_ + lg*32))*8;
    {
        int ll = tid >> 3, u = tid & 7;
        g4[tid] = fP[ll][u ^ (ll & 7)];
    }
    if (tid < 32) {
        float v = 0.f;
        #pragma unroll
        for (int g = 0; g < 8; ++g) v += x2p[g][tid];
        x2buf[n*L_ + lg*32 + tid] = v;
    }
}

// ---------------- Kernel 2: single-pass f16 MFMA distance scan ----------------
__global__ __launch_bounds__(256) void k2_dist(
    const unsigned short* __restrict__ fT, const unsigned short* __restrict__ ph,
    const float* __restrict__ x2buf, float* __restrict__ md_part)
{
    __shared__ unsigned short fB[4096];  // [64 l][64 k] f16, XOR-swizzled rows (8KB)
    __shared__ float x2S[64];

    const int tid  = threadIdx.x;
    const int lane = tid & 63;
    const int wv   = tid >> 6;          // 0..3
    const int n    = blockIdx.y;
    const int lg   = blockIdx.x >> 2;   // 0..7, 64 l each
    const int pg   = blockIdx.x & 3;    // 0..3 proto-tile phase

    {
        const char* gH = (const char*)(fT + ((size_t)n*L_ + lg*64)*CP);
        #pragma unroll
        for (int j = 0; j < 2; ++j) {
            int d  = tid*32 + j*16;
            int lr = d >> 7;
            int bo = d & 127;
            int pb = (lr << 7) + (bo ^ ((lr & 7) << 4));
            *(uint4*)((char*)fB + pb) = *(const uint4*)(gH + d);
        }
    }
    if (tid < 64) x2S[tid] = x2buf[n*L_ + lg*64 + tid];
    __syncthreads();

    const int g  = lane >> 4;           // 0..3
    const int pr = lane & 15;

    f16x8 af[4][2];
    #pragma unroll
    for (int lt = 0; lt < 4; ++lt) {
        int lrow = lt*16 + pr;
        #pragma unroll
        for (int ks = 0; ks < 2; ++ks) {
            int bo = (ks*64 + g*16) ^ ((lrow & 7) << 4);
            af[lt][ks] = *(const f16x8*)((const char*)fB + lrow*128 + bo);
        }
    }
    float4 xv[4];
    #pragma unroll
    for (int lt = 0; lt < 4; ++lt)
        xv[lt] = *(const float4*)&x2S[lt*16 + g*4];

    float* mp = md_part + ((size_t)lg*N_ + n)*P_;

    const int t0 = pg + 4*wv;           // 0..15
    f16x8 b[2], nb[2];
    {
        const int p = t0*16 + pr;
        #pragma unroll
        for (int ks = 0; ks < 2; ++ks)
            b[ks] = *(const f16x8*)(ph + (size_t)p*64 + ks*32 + g*8);
    }
    for (int t = t0; t < P_/16; t += 16) {
        const int tn = t + 16;
        if (tn < P_/16) {
            const int p = tn*16 + pr;
            #pragma unroll
            for (int ks = 0; ks < 2; ++ks)
                nb[ks] = *(const f16x8*)(ph + (size_t)p*64 + ks*32 + g*8);
        }

        float cm0 = 3.0e38f, cm1 = 3.0e38f, cm2 = 3.0e38f, cm3 = 3.0e38f;
        #pragma unroll
        for (int lt = 0; lt < 4; ++lt) {
            f32x4 c = {0.f, 0.f, 0.f, 0.f};
            c = __builtin_amdgcn_mfma_f32_16x16x32_f16(af[lt][0], b[0], c, 0, 0, 0);
            c = __builtin_amdgcn_mfma_f32_16x16x32_f16(af[lt][1], b[1], c, 0, 0, 0);
            cm0 = fminf(cm0, fmaf(-2.f, c[0], xv[lt].x));
            cm1 = fminf(cm1, fmaf(-2.f, c[1], xv[lt].y));
            cm2 = fminf(cm2, fmaf(-2.f, c[2], xv[lt].z));
            cm3 = fminf(cm3, fmaf(-2.f, c[3], xv[lt].w));
        }
        float v = fminf(fminf(cm0, cm1), fminf(cm2, cm3));
        v = fminf(v, __shfl_xor(v, 16));
        v = fminf(v, __shfl_xor(v, 32));
        if (lane < 16) mp[t*16 + lane] = v;

        b[0] = nb[0]; b[1] = nb[1];
    }
}

// ---------------- Kernel 2b: min over 8 l-chunks + p2 + relu + log ----------------
__global__ __launch_bounds__(256) void k2b_reduce(const float* __restrict__ md_part,
    const float* __restrict__ p2, float* __restrict__ md_out, float* __restrict__ acts)
{
    const int p = blockIdx.x*256 + threadIdx.x;
    const int n = blockIdx.y;
    if (p < P_) {
        float mv = 3.0e38f;
        #pragma unroll
        for (int lg = 0; lg < 8; ++lg)
            mv = fminf(mv, md_part[((size_t)lg*N_ + n)*P_ + p]);
        float m = fmaxf(mv + p2[p], 0.0f);
        md_out[n*P_ + p] = m;
        acts[n*P_ + p]   = logf((m + 1.0f) / (m + EPS));
    }
}

// ---------------- Kernel 3: logits = acts @ last_w^T, one wave per output ----------------
__global__ __launch_bounds__(256) void k3_logits(const float* __restrict__ acts,
    const float* __restrict__ last_w, float* __restrict__ out)
{
    const int wid  = (blockIdx.x * 256 + threadIdx.x) >> 6;  // 0..6399
    const int lane = threadIdx.x & 63;
    const int n    = wid / NCLS;
    const int cls  = wid - n * NCLS;

    const float4* a = (const float4*)(acts + (size_t)n*P_);
    const float4* w = (const float4*)(last_w + (size_t)cls*P_);

    float acc = 0.f;
    #pragma unroll
    for (int it = 0; it < 8; ++it) {
        int idx = it*64 + lane;
        if (idx < P_/4) {
            float4 av = a[idx]; float4 wv = w[idx];
            acc += av.x*wv.x + av.y*wv.y + av.z*wv.z + av.w*wv.w;
        }
    }
    #pragma unroll
    for (int off = 32; off > 0; off >>= 1)
        acc += __shfl_down(acc, off);
    if (lane == 0)
        out[n*NCLS + cls] = acc;
}

extern "C" void kernel_launch(void* const* d_in, const int* in_sizes, int n_in,
                              void* d_out, int out_size, void* d_ws, size_t ws_size,
                              hipStream_t stream)
{
    const float* x      = (const float*)d_in[0];
    const float* W1     = (const float*)d_in[1];
    const float* b1     = (const float*)d_in[2];
    const float* W2     = (const float*)d_in[3];
    const float* b2     = (const float*)d_in[4];
    const float* proto  = (const float*)d_in[5];
    const float* last_w = (const float*)d_in[6];

    float* out = (float*)d_out;   // [32*200] logits, then [32*2000] min_dist

    // ws layout (~4.6MB): fT 2MB | x2buf 64KB | acts 256KB | ph 256KB | p2 8KB | md_part 2MB
    unsigned short* fT = (unsigned short*)d_ws;
    float* x2buf = (float*)(fT + (size_t)N_*L_*CP);
    float* acts  = x2buf + (size_t)N_*L_;
    unsigned short* ph = (unsigned short*)(acts + (size_t)N_*P_);
    float* p2      = (float*)(ph + (size_t)P_*CP);
    float* md_part = p2 + P_;

    k0_proto  <<<500,           256, 0, stream>>>(proto, ph, p2);
    // --- MEASUREMENT: k1 launched 3x (idempotent). dur_us delta vs R13 (46.6) = 2x k1. ---
    k1_conv   <<<dim3(16, 32),  256, 0, stream>>>(x, W1, b1, W2, b2, fT, x2buf);
    k1_conv   <<<dim3(16, 32),  256, 0, stream>>>(x, W1, b1, W2, b2, fT, x2buf);
    k1_conv   <<<dim3(16, 32),  256, 0, stream>>>(x, W1, b1, W2, b2, fT, x2buf);
    k2_dist   <<<dim3(32, 32),  256, 0, stream>>>(fT, ph, x2buf, md_part);
    k2b_reduce<<<dim3(8, 32),   256, 0, stream>>>(md_part, p2, out + N_*NCLS, acts);
    k3_logits <<<1600,          256, 0, stream>>>(acts, last_w, out);
}

// Round 16
// 34.683 us; speedup vs baseline: 2.1261x; 2.1261x over previous
//
#include <hip/hip_runtime.h>
#include <hip/hip_fp16.h>
#include <math.h>

#define EPS 1e-4f
#define N_   32
#define CIN  128
#define L_   512
#define CP   64
#define P_   2000
#define NCLS 200

typedef __attribute__((ext_vector_type(8))) _Float16 f16x8;
typedef __attribute__((ext_vector_type(4))) float f32x4;

__device__ inline void gl_lds16(const void* g, void* l) {
    __builtin_amdgcn_global_load_lds(
        (const __attribute__((address_space(1))) unsigned int*)g,
        (__attribute__((address_space(3))) unsigned int*)l, 16, 0, 0);
}
__device__ inline unsigned int packh2(float a, float b) {
    unsigned int lo = __half_as_ushort(__float2half(a));
    unsigned int hi = __half_as_ushort(__float2half(b));
    return lo | (hi << 16);
}

// ---------------- Kernel 0: proto -> f16 + p2; W1,W2 -> f16 ----------------
__global__ __launch_bounds__(256) void k0_proto(const float* __restrict__ proto,
    const float* __restrict__ W1, const float* __restrict__ W2,
    unsigned short* __restrict__ ph, unsigned short* __restrict__ w1h,
    unsigned short* __restrict__ w2h, float* __restrict__ p2)
{
    const int tid = threadIdx.x;
    const int bx  = blockIdx.x;
    if (bx == 500) {            // W1: 64*128 = 8192
        #pragma unroll
        for (int i = 0; i < 32; ++i) {
            int idx = i*256 + tid;
            w1h[idx] = __half_as_ushort(__float2half(W1[idx]));
        }
        return;
    }
    if (bx == 501) {            // W2: 64*64 = 4096
        #pragma unroll
        for (int i = 0; i < 16; ++i) {
            int idx = i*256 + tid;
            w2h[idx] = __half_as_ushort(__float2half(W2[idx]));
        }
        return;
    }
    const int p = bx*4 + (tid >> 6);
    const int k = tid & 63;
    float v = proto[(size_t)p*64 + k];
    ph[(size_t)p*64 + k] = __half_as_ushort(__float2half(v));
    float s = v*v;
    #pragma unroll
    for (int off = 32; off > 0; off >>= 1) s += __shfl_xor(s, off);
    if (k == 0) p2[p] = s;
}

// ---------------- Kernel 1: conv-relu-conv-sigmoid via f16 MFMA ----------------
// grid (16 lg, 32 n) x 256 thr (4 waves). Block = 32 l. Wave = (lt = wv&1, oh = wv>>1).
// A (weights) read directly from global f16 (L1-resident); x staged via global_load_lds.
__global__ __launch_bounds__(256) void k1_conv(const float* __restrict__ x,
    const unsigned short* __restrict__ w1h, const float* __restrict__ b1,
    const unsigned short* __restrict__ w2h, const float* __restrict__ b2,
    unsigned short* __restrict__ fT, float* __restrict__ x2buf)
{
    __shared__ float xS[128*32];                 // 16KB [c][l]; first 4.6KB reused as gb
    __shared__ __align__(16) unsigned short hb[32*72];  // [l][o] f16, 144B rows (9.2->4.6KB)
    __shared__ float x2p[2][32];

    const int tid  = threadIdx.x;
    const int lane = tid & 63;
    const int wv   = tid >> 6;
    const int n    = blockIdx.y;
    const int lg   = blockIdx.x;          // 0..15, 32 l each

    // ---- stage x tile [128 c][32 l] f32 (async, linear dest) ----
    {
        const float* xbase = x + (size_t)n*CIN*L_ + lg*32;
        #pragma unroll
        for (int i = 0; i < 4; ++i) {
            int blk = wv*4 + i;               // 1KB chunk = 8 c rows
            const float* src = xbase + (size_t)(blk*8 + (lane >> 3))*L_ + (lane & 7)*4;
            gl_lds16(src, &xS[blk*256]);
        }
    }
    __syncthreads();

    const int r  = lane & 15;
    const int g  = lane >> 4;
    const int lt = wv & 1;                // l-tile (16 l)
    const int oh = wv >> 1;               // o-half (2 o-tiles)
    const int lrow = lt*16 + r;

    // ---- conv1: h[o][l] = relu(W1 @ x + b1), D[o][l] via 16x16x32 f16 MFMA ----
    f32x4 acc[2];
    #pragma unroll
    for (int o2 = 0; o2 < 2; ++o2)
        acc[o2] = *(const f32x4*)(b1 + (oh*2 + o2)*16 + g*4);

    #pragma unroll
    for (int ks = 0; ks < 4; ++ks) {
        f16x8 B;
        #pragma unroll
        for (int i = 0; i < 8; ++i)
            B[i] = (_Float16)xS[(ks*32 + g*8 + i)*32 + lrow];
        #pragma unroll
        for (int o2 = 0; o2 < 2; ++o2) {
            int ot = oh*2 + o2;
            f16x8 A = *(const f16x8*)(w1h + (ot*16 + r)*128 + ks*32 + g*8);
            acc[o2] = __builtin_amdgcn_mfma_f32_16x16x32_f16(A, B, acc[o2], 0, 0, 0);
        }
    }
    // relu -> f16 -> hb[l][o] (144B rows). Same-wave rows: no barrier needed before read.
    #pragma unroll
    for (int o2 = 0; o2 < 2; ++o2) {
        int ot = oh*2 + o2;
        float v0 = fmaxf(acc[o2][0], 0.f), v1 = fmaxf(acc[o2][1], 0.f);
        float v2 = fmaxf(acc[o2][2], 0.f), v3 = fmaxf(acc[o2][3], 0.f);
        uint2 w2v = make_uint2(packh2(v0, v1), packh2(v2, v3));
        *(uint2*)((char*)hb + lrow*144 + ot*32 + g*8) = w2v;
    }
    __syncthreads();   // hb complete across waves (conv2 k spans all o) ; xS reads done

    // ---- conv2: f = sigmoid(W2 @ h + b2) ----
    f32x4 acc2[2];
    #pragma unroll
    for (int o2 = 0; o2 < 2; ++o2)
        acc2[o2] = *(const f32x4*)(b2 + (oh*2 + o2)*16 + g*4);

    #pragma unroll
    for (int ks = 0; ks < 2; ++ks) {
        f16x8 B = *(const f16x8*)((const char*)hb + lrow*144 + ks*64 + g*16);
        #pragma unroll
        for (int o2 = 0; o2 < 2; ++o2) {
            int ot = oh*2 + o2;
            f16x8 A = *(const f16x8*)(w2h + (ot*16 + r)*64 + ks*32 + g*8);
            acc2[o2] = __builtin_amdgcn_mfma_f32_16x16x32_f16(A, B, acc2[o2], 0, 0, 0);
        }
    }

    // ---- sigmoid, x2 partial, pack f16 into gb (aliases xS; xS dead after barrier) ----
    char* gb = (char*)xS;                 // [32 l][144B] rows
    float s = 0.f;
    float fv[2][4];
    #pragma unroll
    for (int o2 = 0; o2 < 2; ++o2)
        #pragma unroll
        for (int j = 0; j < 4; ++j) {
            float v = 1.f/(1.f + expf(-acc2[o2][j]));
            fv[o2][j] = v;
            s = fmaf(v, v, s);
        }
    s += __shfl_xor(s, 16);
    s += __shfl_xor(s, 32);
    if (lane < 16) x2p[oh][lrow] = s;     // sum over this wave's 32 o-channels

    #pragma unroll
    for (int o2 = 0; o2 < 2; ++o2) {
        int ot = oh*2 + o2;
        uint2 w2v = make_uint2(packh2(fv[o2][0], fv[o2][1]), packh2(fv[o2][2], fv[o2][3]));
        *(uint2*)(gb + lrow*144 + ot*32 + g*8) = w2v;
    }
    __syncthreads();

    // ---- coalesced store: [n][l][c] f16, 32 l x 8 uint4 ----
    {
        int l = tid >> 3, u = tid & 7;
        uint4 v = *(const uint4*)(gb + l*144 + u*16);
        ((uint4*)fT)[((size_t)(n*L_ + lg*32 + l))*8 + u] = v;
    }
    if (tid < 32)
        x2buf[n*L_ + lg*32 + tid] = x2p[0][tid] + x2p[1][tid];
}

// ---------------- Kernel 2: single-pass f16 MFMA distance scan (R13, unchanged) ----------
__global__ __launch_bounds__(256) void k2_dist(
    const unsigned short* __restrict__ fT, const unsigned short* __restrict__ ph,
    const float* __restrict__ x2buf, float* __restrict__ md_part)
{
    __shared__ unsigned short fB[4096];  // [64 l][64 k] f16, XOR-swizzled rows (8KB)
    __shared__ float x2S[64];

    const int tid  = threadIdx.x;
    const int lane = tid & 63;
    const int wv   = tid >> 6;          // 0..3
    const int n    = blockIdx.y;
    const int lg   = blockIdx.x >> 2;   // 0..7, 64 l each
    const int pg   = blockIdx.x & 3;    // 0..3 proto-tile phase

    {
        const char* gH = (const char*)(fT + ((size_t)n*L_ + lg*64)*CP);
        #pragma unroll
        for (int j = 0; j < 2; ++j) {
            int d  = tid*32 + j*16;
            int lr = d >> 7;
            int bo = d & 127;
            int pb = (lr << 7) + (bo ^ ((lr & 7) << 4));
            *(uint4*)((char*)fB + pb) = *(const uint4*)(gH + d);
        }
    }
    if (tid < 64) x2S[tid] = x2buf[n*L_ + lg*64 + tid];
    __syncthreads();

    const int g  = lane >> 4;           // 0..3
    const int pr = lane & 15;

    f16x8 af[4][2];
    #pragma unroll
    for (int lt = 0; lt < 4; ++lt) {
        int lrow = lt*16 + pr;
        #pragma unroll
        for (int ks = 0; ks < 2; ++ks) {
            int bo = (ks*64 + g*16) ^ ((lrow & 7) << 4);
            af[lt][ks] = *(const f16x8*)((const char*)fB + lrow*128 + bo);
        }
    }
    float4 xv[4];
    #pragma unroll
    for (int lt = 0; lt < 4; ++lt)
        xv[lt] = *(const float4*)&x2S[lt*16 + g*4];

    float* mp = md_part + ((size_t)lg*N_ + n)*P_;

    const int t0 = pg + 4*wv;           // 0..15
    f16x8 b[2], nb[2];
    {
        const int p = t0*16 + pr;
        #pragma unroll
        for (int ks = 0; ks < 2; ++ks)
            b[ks] = *(const f16x8*)(ph + (size_t)p*64 + ks*32 + g*8);
    }
    for (int t = t0; t < P_/16; t += 16) {
        const int tn = t + 16;
        if (tn < P_/16) {
            const int p = tn*16 + pr;
            #pragma unroll
            for (int ks = 0; ks < 2; ++ks)
                nb[ks] = *(const f16x8*)(ph + (size_t)p*64 + ks*32 + g*8);
        }

        float cm0 = 3.0e38f, cm1 = 3.0e38f, cm2 = 3.0e38f, cm3 = 3.0e38f;
        #pragma unroll
        for (int lt = 0; lt < 4; ++lt) {
            f32x4 c = {0.f, 0.f, 0.f, 0.f};
            c = __builtin_amdgcn_mfma_f32_16x16x32_f16(af[lt][0], b[0], c, 0, 0, 0);
            c = __builtin_amdgcn_mfma_f32_16x16x32_f16(af[lt][1], b[1], c, 0, 0, 0);
            cm0 = fminf(cm0, fmaf(-2.f, c[0], xv[lt].x));
            cm1 = fminf(cm1, fmaf(-2.f, c[1], xv[lt].y));
            cm2 = fminf(cm2, fmaf(-2.f, c[2], xv[lt].z));
            cm3 = fminf(cm3, fmaf(-2.f, c[3], xv[lt].w));
        }
        float v = fminf(fminf(cm0, cm1), fminf(cm2, cm3));
        v = fminf(v, __shfl_xor(v, 16));
        v = fminf(v, __shfl_xor(v, 32));
        if (lane < 16) mp[t*16 + lane] = v;

        b[0] = nb[0]; b[1] = nb[1];
    }
}

// ---------------- Kernel 2b: min over 8 l-chunks + p2 + relu + log ----------------
__global__ __launch_bounds__(256) void k2b_reduce(const float* __restrict__ md_part,
    const float* __restrict__ p2, float* __restrict__ md_out, float* __restrict__ acts)
{
    const int p = blockIdx.x*256 + threadIdx.x;
    const int n = blockIdx.y;
    if (p < P_) {
        float mv = 3.0e38f;
        #pragma unroll
        for (int lg = 0; lg < 8; ++lg)
            mv = fminf(mv, md_part[((size_t)lg*N_ + n)*P_ + p]);
        float m = fmaxf(mv + p2[p], 0.0f);
        md_out[n*P_ + p] = m;
        acts[n*P_ + p]   = logf((m + 1.0f) / (m + EPS));
    }
}

// ---------------- Kernel 3: logits = acts @ last_w^T, one wave per output ----------------
__global__ __launch_bounds__(256) void k3_logits(const float* __restrict__ acts,
    const float* __restrict__ last_w, float* __restrict__ out)
{
    const int wid  = (blockIdx.x * 256 + threadIdx.x) >> 6;  // 0..6399
    const int lane = threadIdx.x & 63;
    const int n    = wid / NCLS;
    const int cls  = wid - n * NCLS;

    const float4* a = (const float4*)(acts + (size_t)n*P_);
    const float4* w = (const float4*)(last_w + (size_t)cls*P_);

    float acc = 0.f;
    #pragma unroll
    for (int it = 0; it < 8; ++it) {
        int idx = it*64 + lane;
        if (idx < P_/4) {
            float4 av = a[idx]; float4 wv = w[idx];
            acc += av.x*wv.x + av.y*wv.y + av.z*wv.z + av.w*wv.w;
        }
    }
    #pragma unroll
    for (int off = 32; off > 0; off >>= 1)
        acc += __shfl_down(acc, off);
    if (lane == 0)
        out[n*NCLS + cls] = acc;
}

extern "C" void kernel_launch(void* const* d_in, const int* in_sizes, int n_in,
                              void* d_out, int out_size, void* d_ws, size_t ws_size,
                              hipStream_t stream)
{
    const float* x      = (const float*)d_in[0];
    const float* W1     = (const float*)d_in[1];
    const float* b1     = (const float*)d_in[2];
    const float* W2     = (const float*)d_in[3];
    const float* b2     = (const float*)d_in[4];
    const float* proto  = (const float*)d_in[5];
    const float* last_w = (const float*)d_in[6];

    float* out = (float*)d_out;   // [32*200] logits, then [32*2000] min_dist

    // ws: fT 2MB | x2buf 64KB | acts 256KB | ph 256KB | p2 8KB | md_part 2MB | w1h 16KB | w2h 8KB
    unsigned short* fT = (unsigned short*)d_ws;
    float* x2buf = (float*)(fT + (size_t)N_*L_*CP);
    float* acts  = x2buf + (size_t)N_*L_;
    unsigned short* ph = (unsigned short*)(acts + (size_t)N_*P_);
    float* p2      = (float*)(ph + (size_t)P_*CP);
    float* md_part = p2 + P_;
    unsigned short* w1h = (unsigned short*)(md_part + (size_t)8*N_*P_);
    unsigned short* w2h = w1h + 64*128;

    k0_proto  <<<502,           256, 0, stream>>>(proto, W1, W2, ph, w1h, w2h, p2);
    k1_conv   <<<dim3(16, 32),  256, 0, stream>>>(x, w1h, b1, w2h, b2, fT, x2buf);
    k2_dist   <<<dim3(32, 32),  256, 0, stream>>>(fT, ph, x2buf, md_part);
    k2b_reduce<<<dim3(8, 32),   256, 0, stream>>>(md_part, p2, out + N_*NCLS, acts);
    k3_logits <<<1600,          256, 0, stream>>>(acts, last_w, out);
}

// Round 17
// 33.794 us; speedup vs baseline: 2.1820x; 1.0263x over previous
//
#include <hip/hip_runtime.h>
#include <hip/hip_fp16.h>
#include <math.h>

#define EPS 1e-4f
#define N_   32
#define CIN  128
#define L_   512
#define CP   64
#define P_   2000
#define NCLS 200

typedef __attribute__((ext_vector_type(8))) _Float16 f16x8;
typedef __attribute__((ext_vector_type(4))) float f32x4;

__device__ inline void gl_lds16(const void* g, void* l) {
    __builtin_amdgcn_global_load_lds(
        (const __attribute__((address_space(1))) unsigned int*)g,
        (__attribute__((address_space(3))) unsigned int*)l, 16, 0, 0);
}
__device__ inline unsigned int packh2(float a, float b) {
    unsigned int lo = __half_as_ushort(__float2half(a));
    unsigned int hi = __half_as_ushort(__float2half(b));
    return lo | (hi << 16);
}
__device__ inline unsigned short f2bf_rne(float f) {
    unsigned int u = __float_as_uint(f);
    unsigned int r = u + 0x7FFFu + ((u >> 16) & 1u);
    return (unsigned short)(r >> 16);
}
__device__ inline float bfdot2(unsigned a, unsigned b, float acc) {
    float a0 = __uint_as_float(a << 16);
    float a1 = __uint_as_float(a & 0xFFFF0000u);
    float b0 = __uint_as_float(b << 16);
    float b1 = __uint_as_float(b & 0xFFFF0000u);
    return fmaf(a1, b1, fmaf(a0, b0, acc));
}

// ---------------- Kernel 0: proto->f16+p2 | W1,W2->f16 | last_w->bf16 ----------------
__global__ __launch_bounds__(256) void k0_proto(const float* __restrict__ proto,
    const float* __restrict__ W1, const float* __restrict__ W2,
    const float* __restrict__ last_w,
    unsigned short* __restrict__ ph, unsigned short* __restrict__ w1h,
    unsigned short* __restrict__ w2h, unsigned short* __restrict__ lwB,
    float* __restrict__ p2)
{
    const int tid = threadIdx.x;
    const int bx  = blockIdx.x;
    if (bx >= 502) {            // last_w: 200*2000 f32 -> bf16, 8 per thread
        int idx8 = (bx - 502)*256 + tid;        // 0..50175
        if (idx8 < 50000) {
            const float4* src = (const float4*)(last_w + (size_t)idx8*8);
            float4 v0 = src[0], v1 = src[1];
            unsigned short o[8] = { f2bf_rne(v0.x), f2bf_rne(v0.y), f2bf_rne(v0.z), f2bf_rne(v0.w),
                                    f2bf_rne(v1.x), f2bf_rne(v1.y), f2bf_rne(v1.z), f2bf_rne(v1.w) };
            *(uint4*)(lwB + (size_t)idx8*8) = *(const uint4*)o;
        }
        return;
    }
    if (bx == 500) {            // W1: 64*128 = 8192
        #pragma unroll
        for (int i = 0; i < 32; ++i) {
            int idx = i*256 + tid;
            w1h[idx] = __half_as_ushort(__float2half(W1[idx]));
        }
        return;
    }
    if (bx == 501) {            // W2: 64*64 = 4096
        #pragma unroll
        for (int i = 0; i < 16; ++i) {
            int idx = i*256 + tid;
            w2h[idx] = __half_as_ushort(__float2half(W2[idx]));
        }
        return;
    }
    const int p = bx*4 + (tid >> 6);
    const int k = tid & 63;
    float v = proto[(size_t)p*64 + k];
    ph[(size_t)p*64 + k] = __half_as_ushort(__float2half(v));
    float s = v*v;
    #pragma unroll
    for (int off = 32; off > 0; off >>= 1) s += __shfl_xor(s, off);
    if (k == 0) p2[p] = s;
}

// ---------------- Kernel 1: conv-relu-conv-sigmoid via f16 MFMA (R16, unchanged) --------
__global__ __launch_bounds__(256) void k1_conv(const float* __restrict__ x,
    const unsigned short* __restrict__ w1h, const float* __restrict__ b1,
    const unsigned short* __restrict__ w2h, const float* __restrict__ b2,
    unsigned short* __restrict__ fT, float* __restrict__ x2buf)
{
    __shared__ float xS[128*32];                 // 16KB [c][l]; reused as gb
    __shared__ __align__(16) unsigned short hb[32*72];  // [l][o] f16, 144B rows
    __shared__ float x2p[2][32];

    const int tid  = threadIdx.x;
    const int lane = tid & 63;
    const int wv   = tid >> 6;
    const int n    = blockIdx.y;
    const int lg   = blockIdx.x;          // 0..15, 32 l each

    {
        const float* xbase = x + (size_t)n*CIN*L_ + lg*32;
        #pragma unroll
        for (int i = 0; i < 4; ++i) {
            int blk = wv*4 + i;
            const float* src = xbase + (size_t)(blk*8 + (lane >> 3))*L_ + (lane & 7)*4;
            gl_lds16(src, &xS[blk*256]);
        }
    }
    __syncthreads();

    const int r  = lane & 15;
    const int g  = lane >> 4;
    const int lt = wv & 1;
    const int oh = wv >> 1;
    const int lrow = lt*16 + r;

    f32x4 acc[2];
    #pragma unroll
    for (int o2 = 0; o2 < 2; ++o2)
        acc[o2] = *(const f32x4*)(b1 + (oh*2 + o2)*16 + g*4);

    #pragma unroll
    for (int ks = 0; ks < 4; ++ks) {
        f16x8 B;
        #pragma unroll
        for (int i = 0; i < 8; ++i)
            B[i] = (_Float16)xS[(ks*32 + g*8 + i)*32 + lrow];
        #pragma unroll
        for (int o2 = 0; o2 < 2; ++o2) {
            int ot = oh*2 + o2;
            f16x8 A = *(const f16x8*)(w1h + (ot*16 + r)*128 + ks*32 + g*8);
            acc[o2] = __builtin_amdgcn_mfma_f32_16x16x32_f16(A, B, acc[o2], 0, 0, 0);
        }
    }
    #pragma unroll
    for (int o2 = 0; o2 < 2; ++o2) {
        int ot = oh*2 + o2;
        float v0 = fmaxf(acc[o2][0], 0.f), v1 = fmaxf(acc[o2][1], 0.f);
        float v2 = fmaxf(acc[o2][2], 0.f), v3 = fmaxf(acc[o2][3], 0.f);
        uint2 w2v = make_uint2(packh2(v0, v1), packh2(v2, v3));
        *(uint2*)((char*)hb + lrow*144 + ot*32 + g*8) = w2v;
    }
    __syncthreads();

    f32x4 acc2[2];
    #pragma unroll
    for (int o2 = 0; o2 < 2; ++o2)
        acc2[o2] = *(const f32x4*)(b2 + (oh*2 + o2)*16 + g*4);

    #pragma unroll
    for (int ks = 0; ks < 2; ++ks) {
        f16x8 B = *(const f16x8*)((const char*)hb + lrow*144 + ks*64 + g*16);
        #pragma unroll
        for (int o2 = 0; o2 < 2; ++o2) {
            int ot = oh*2 + o2;
            f16x8 A = *(const f16x8*)(w2h + (ot*16 + r)*64 + ks*32 + g*8);
            acc2[o2] = __builtin_amdgcn_mfma_f32_16x16x32_f16(A, B, acc2[o2], 0, 0, 0);
        }
    }

    char* gb = (char*)xS;
    float s = 0.f;
    float fv[2][4];
    #pragma unroll
    for (int o2 = 0; o2 < 2; ++o2)
        #pragma unroll
        for (int j = 0; j < 4; ++j) {
            float v = 1.f/(1.f + expf(-acc2[o2][j]));
            fv[o2][j] = v;
            s = fmaf(v, v, s);
        }
    s += __shfl_xor(s, 16);
    s += __shfl_xor(s, 32);
    if (lane < 16) x2p[oh][lrow] = s;

    #pragma unroll
    for (int o2 = 0; o2 < 2; ++o2) {
        int ot = oh*2 + o2;
        uint2 w2v = make_uint2(packh2(fv[o2][0], fv[o2][1]), packh2(fv[o2][2], fv[o2][3]));
        *(uint2*)(gb + lrow*144 + ot*32 + g*8) = w2v;
    }
    __syncthreads();

    {
        int l = tid >> 3, u = tid & 7;
        uint4 v = *(const uint4*)(gb + l*144 + u*16);
        ((uint4*)fT)[((size_t)(n*L_ + lg*32 + l))*8 + u] = v;
    }
    if (tid < 32)
        x2buf[n*L_ + lg*32 + tid] = x2p[0][tid] + x2p[1][tid];
}

// ---------------- Kernel 2: f16 MFMA distance scan, 2-deep prefetch ----------------
__global__ __launch_bounds__(256) void k2_dist(
    const unsigned short* __restrict__ fT, const unsigned short* __restrict__ ph,
    const float* __restrict__ x2buf, float* __restrict__ md_part)
{
    __shared__ unsigned short fB[4096];  // [64 l][64 k] f16, XOR-swizzled rows (8KB)
    __shared__ float x2S[64];

    const int tid  = threadIdx.x;
    const int lane = tid & 63;
    const int wv   = tid >> 6;          // 0..3
    const int n    = blockIdx.y;
    const int lg   = blockIdx.x >> 2;   // 0..7, 64 l each
    const int pg   = blockIdx.x & 3;    // 0..3 proto-tile phase

    {
        const char* gH = (const char*)(fT + ((size_t)n*L_ + lg*64)*CP);
        #pragma unroll
        for (int j = 0; j < 2; ++j) {
            int d  = tid*32 + j*16;
            int lr = d >> 7;
            int bo = d & 127;
            int pb = (lr << 7) + (bo ^ ((lr & 7) << 4));
            *(uint4*)((char*)fB + pb) = *(const uint4*)(gH + d);
        }
    }
    if (tid < 64) x2S[tid] = x2buf[n*L_ + lg*64 + tid];
    __syncthreads();

    const int g  = lane >> 4;           // 0..3
    const int pr = lane & 15;

    f16x8 af[4][2];
    #pragma unroll
    for (int lt = 0; lt < 4; ++lt) {
        int lrow = lt*16 + pr;
        #pragma unroll
        for (int ks = 0; ks < 2; ++ks) {
            int bo = (ks*64 + g*16) ^ ((lrow & 7) << 4);
            af[lt][ks] = *(const f16x8*)((const char*)fB + lrow*128 + bo);
        }
    }
    float4 xv[4];
    #pragma unroll
    for (int lt = 0; lt < 4; ++lt)
        xv[lt] = *(const float4*)&x2S[lt*16 + g*4];

    float* mp = md_part + ((size_t)lg*N_ + n)*P_;

    const int t0 = pg + 4*wv;           // 0..15; tiles t0, t0+16, ... < 125
    f16x8 bA[2], bB[2], bC[2];
    {
        const int p = t0*16 + pr;
        #pragma unroll
        for (int ks = 0; ks < 2; ++ks)
            bA[ks] = *(const f16x8*)(ph + (size_t)p*64 + ks*32 + g*8);
    }
    if (t0 + 16 < P_/16) {
        const int p = (t0+16)*16 + pr;
        #pragma unroll
        for (int ks = 0; ks < 2; ++ks)
            bB[ks] = *(const f16x8*)(ph + (size_t)p*64 + ks*32 + g*8);
    }
    for (int t = t0; t < P_/16; t += 16) {
        const int t2 = t + 32;
        if (t2 < P_/16) {
            const int p = t2*16 + pr;
            #pragma unroll
            for (int ks = 0; ks < 2; ++ks)
                bC[ks] = *(const f16x8*)(ph + (size_t)p*64 + ks*32 + g*8);
        }

        float cm0 = 3.0e38f, cm1 = 3.0e38f, cm2 = 3.0e38f, cm3 = 3.0e38f;
        #pragma unroll
        for (int lt = 0; lt < 4; ++lt) {
            f32x4 c = {0.f, 0.f, 0.f, 0.f};
            c = __builtin_amdgcn_mfma_f32_16x16x32_f16(af[lt][0], bA[0], c, 0, 0, 0);
            c = __builtin_amdgcn_mfma_f32_16x16x32_f16(af[lt][1], bA[1], c, 0, 0, 0);
            cm0 = fminf(cm0, fmaf(-2.f, c[0], xv[lt].x));
            cm1 = fminf(cm1, fmaf(-2.f, c[1], xv[lt].y));
            cm2 = fminf(cm2, fmaf(-2.f, c[2], xv[lt].z));
            cm3 = fminf(cm3, fmaf(-2.f, c[3], xv[lt].w));
        }
        float v = fminf(fminf(cm0, cm1), fminf(cm2, cm3));
        v = fminf(v, __shfl_xor(v, 16));
        v = fminf(v, __shfl_xor(v, 32));
        if (lane < 16) mp[t*16 + lane] = v;

        bA[0] = bB[0]; bA[1] = bB[1];
        bB[0] = bC[0]; bB[1] = bC[1];
    }
}

// ---------------- Kernel 2b: min over 8 l-chunks + p2 + relu + log -> f32 md, bf16 acts --
__global__ __launch_bounds__(256) void k2b_reduce(const float* __restrict__ md_part,
    const float* __restrict__ p2, float* __restrict__ md_out,
    unsigned short* __restrict__ actsB)
{
    const int p = blockIdx.x*256 + threadIdx.x;
    const int n = blockIdx.y;
    if (p < P_) {
        float mv = 3.0e38f;
        #pragma unroll
        for (int lg = 0; lg < 8; ++lg)
            mv = fminf(mv, md_part[((size_t)lg*N_ + n)*P_ + p]);
        float m = fmaxf(mv + p2[p], 0.0f);
        md_out[n*P_ + p] = m;
        actsB[(size_t)n*P_ + p] = f2bf_rne(logf((m + 1.0f) / (m + EPS)));
    }
}

// ---------------- Kernel 3: logits from bf16 acts/last_w, one wave per output ----------
__global__ __launch_bounds__(256) void k3_logits(const unsigned short* __restrict__ actsB,
    const unsigned short* __restrict__ lwB, float* __restrict__ out)
{
    const int wid  = (blockIdx.x * 256 + threadIdx.x) >> 6;  // 0..6399
    const int lane = threadIdx.x & 63;
    const int n    = wid / NCLS;
    const int cls  = wid - n * NCLS;

    const uint4* a = (const uint4*)(actsB + (size_t)n*P_);   // 250 uint4 per row
    const uint4* w = (const uint4*)(lwB + (size_t)cls*P_);

    float acc = 0.f;
    #pragma unroll
    for (int it = 0; it < 4; ++it) {
        int idx = it*64 + lane;          // 0..255
        if (idx < P_/8) {
            uint4 av = a[idx], wv = w[idx];
            acc = bfdot2(av.x, wv.x, acc);
            acc = bfdot2(av.y, wv.y, acc);
            acc = bfdot2(av.z, wv.z, acc);
            acc = bfdot2(av.w, wv.w, acc);
        }
    }
    #pragma unroll
    for (int off = 32; off > 0; off >>= 1)
        acc += __shfl_down(acc, off);
    if (lane == 0)
        out[n*NCLS + cls] = acc;
}

extern "C" void kernel_launch(void* const* d_in, const int* in_sizes, int n_in,
                              void* d_out, int out_size, void* d_ws, size_t ws_size,
                              hipStream_t stream)
{
    const float* x      = (const float*)d_in[0];
    const float* W1     = (const float*)d_in[1];
    const float* b1     = (const float*)d_in[2];
    const float* W2     = (const float*)d_in[3];
    const float* b2     = (const float*)d_in[4];
    const float* proto  = (const float*)d_in[5];
    const float* last_w = (const float*)d_in[6];

    float* out = (float*)d_out;   // [32*200] logits, then [32*2000] min_dist

    // ws (~5.3MB): fT 2MB | x2buf 64KB | actsB 128KB | ph 256KB | p2 8KB | md_part 2MB
    //             | w1h 16KB | w2h 8KB | lwB 800KB
    unsigned short* fT = (unsigned short*)d_ws;
    float* x2buf = (float*)(fT + (size_t)N_*L_*CP);
    unsigned short* actsB = (unsigned short*)(x2buf + (size_t)N_*L_);
    unsigned short* ph = actsB + (size_t)N_*P_;
    float* p2      = (float*)(ph + (size_t)P_*CP);
    float* md_part = p2 + P_;
    unsigned short* w1h = (unsigned short*)(md_part + (size_t)8*N_*P_);
    unsigned short* w2h = w1h + 64*CIN;
    unsigned short* lwB = w2h + 64*CP;

    k0_proto  <<<698,           256, 0, stream>>>(proto, W1, W2, last_w,
                                                  ph, w1h, w2h, lwB, p2);
    k1_conv   <<<dim3(16, 32),  256, 0, stream>>>(x, w1h, b1, w2h, b2, fT, x2buf);
    k2_dist   <<<dim3(32, 32),  256, 0, stream>>>(fT, ph, x2buf, md_part);
    k2b_reduce<<<dim3(8, 32),   256, 0, stream>>>(md_part, p2, out + N_*NCLS, actsB);
    k3_logits <<<1600,          256, 0, stream>>>(actsB, lwB, out);
}